// Round 1
// baseline (374.049 us; speedup 1.0000x reference)
//
#include <hip/hip_runtime.h>
#include <hip/hip_bf16.h>

#define B_ 4
#define C_ 256
#define N_ 4096
#define D_ 32   // C/8

typedef __bf16 bf16_t;
typedef __bf16 bf16x8 __attribute__((ext_vector_type(8)));
typedef float  f32x4  __attribute__((ext_vector_type(4)));

// ---------------------------------------------------------------------------
// Projection: [320,256] x [256,4096] per batch. Rows 0-31 = Wq, 32-63 = Wk,
// 64-319 = Wv. Outputs bf16: Qh/Kh as [B][N][32] (token-major), Vh [B][256][N].
// grid (N/64, 320/64, B), block 256.
// ---------------------------------------------------------------------------
__global__ __launch_bounds__(256) void proj_kernel(
    const float* __restrict__ x,
    const float* __restrict__ wq, const float* __restrict__ bq,
    const float* __restrict__ wk, const float* __restrict__ bk,
    const float* __restrict__ wv, const float* __restrict__ bv,
    bf16_t* __restrict__ Qh, bf16_t* __restrict__ Kh, bf16_t* __restrict__ Vh)
{
  const int n0 = blockIdx.x * 64;
  const int r0 = blockIdx.y * 64;
  const int b  = blockIdx.z;
  __shared__ float xs[32][64];
  __shared__ float wsm[64][33];
  const int t  = threadIdx.x;
  const int tx = t & 63;   // n within tile
  const int ty = t >> 6;   // row quarter

  float acc[16];
#pragma unroll
  for (int i = 0; i < 16; ++i) acc[i] = 0.f;

  for (int c0 = 0; c0 < C_; c0 += 32) {
    __syncthreads();
#pragma unroll
    for (int i = 0; i < 8; ++i) {
      int idx = t + i * 256;
      int r = idx >> 6, cc = idx & 63;
      xs[r][cc] = x[(size_t)b * C_ * N_ + (size_t)(c0 + r) * N_ + n0 + cc];
    }
#pragma unroll
    for (int i = 0; i < 8; ++i) {
      int idx = t + i * 256;
      int r = idx >> 5, cc = idx & 31;
      int gr = r0 + r;
      float w;
      if (gr < 32)      w = wq[gr * C_ + c0 + cc];
      else if (gr < 64) w = wk[(gr - 32) * C_ + c0 + cc];
      else              w = wv[(gr - 64) * C_ + c0 + cc];
      wsm[r][cc] = w;
    }
    __syncthreads();
#pragma unroll
    for (int c = 0; c < 32; ++c) {
      float xv = xs[c][tx];
#pragma unroll
      for (int i = 0; i < 16; ++i)
        acc[i] += wsm[ty * 16 + i][c] * xv;
    }
  }

  const int n = n0 + tx;
#pragma unroll
  for (int i = 0; i < 16; ++i) {
    int gr = r0 + ty * 16 + i;
    if (gr < 32) {
      float v = acc[i] + bq[gr];
      Qh[((size_t)b * N_ + n) * D_ + gr] = (bf16_t)v;
    } else if (gr < 64) {
      float v = acc[i] + bk[gr - 32];
      Kh[((size_t)b * N_ + n) * D_ + (gr - 32)] = (bf16_t)v;
    } else {
      float v = acc[i] + bv[gr - 64];
      Vh[((size_t)b * C_ + (gr - 64)) * N_ + n] = (bf16_t)v;
    }
  }
}

// ---------------------------------------------------------------------------
// Flash attention + epilogue (gamma*out + x).
// 256 blocks x 512 threads (8 waves). Block = 64 q-rows x 256 v-channels.
// Wave = 32 q-rows (wid&1) x 64 v-channels (wid>>1). Key tile MB=64.
// MFMA 16x16x32 bf16; verified C/D layout: col=lane&15, row=4*(lane>>4)+reg.
// A-frag: lane = 16*(k/8)+row, 8 contiguous k per lane.
// B-frag: lane = 16*(k/8)+col, 8 contiguous k per lane.
// XCD swizzle: each XCD sees exactly one batch -> K+V (2.25MB) L2-resident.
// ---------------------------------------------------------------------------
#define QB 64
#define MB 64

__global__ __launch_bounds__(512, 2) void attn_kernel(
    const bf16_t* __restrict__ Qh, const bf16_t* __restrict__ Kh,
    const bf16_t* __restrict__ Vh,
    const float* __restrict__ x, const float* __restrict__ gamma,
    float* __restrict__ out)
{
  __shared__ bf16_t Vt[C_][72];      // V tile [c][m], pad 72 halves (16B-aligned rows)
  __shared__ bf16_t Pl[8][32][72];   // per-wave P scratch [row][m]

  const int bi   = blockIdx.x;
  const int xcd  = bi & 7;           // blockIdx round-robins XCDs
  const int slot = bi >> 3;          // 0..31
  const int b    = xcd >> 1;         // batch: 2 XCDs per batch
  const int qt   = (xcd & 1) * 32 + slot;
  const int q0   = qt * QB;

  const int t    = threadIdx.x;
  const int wid  = t >> 6;
  const int lane = t & 63;
  const int l4   = lane >> 4;
  const int lm   = lane & 15;

  const int rowhalf = wid & 1;
  const int cq      = wid >> 1;
  const int R0      = q0 + rowhalf * 32;
  const int c0      = cq * 64;

  const f32x4 z4 = {0.f, 0.f, 0.f, 0.f};

  // Q fragments, held in registers for the whole kernel
  bf16x8 qf[2];
#pragma unroll
  for (int rt = 0; rt < 2; ++rt)
    qf[rt] = *(const bf16x8*)(Qh + ((size_t)b * N_ + R0 + rt * 16 + lm) * D_ + l4 * 8);

  f32x4 acc[2][4];
#pragma unroll
  for (int rt = 0; rt < 2; ++rt)
#pragma unroll
    for (int ct = 0; ct < 4; ++ct) acc[rt][ct] = z4;

  float m_run[2][4], l_run[2][4];
#pragma unroll
  for (int rt = 0; rt < 2; ++rt)
#pragma unroll
    for (int r = 0; r < 4; ++r) { m_run[rt][r] = -1e30f; l_run[rt][r] = 0.f; }

  const int vc = t >> 1;   // V stage: each thread copies 64B of one channel row
  const int vh = t & 1;
  const bf16_t* vsrc_base = Vh + ((size_t)b * C_ + vc) * (size_t)N_ + vh * 32;

#pragma unroll 1
  for (int m0 = 0; m0 < N_; m0 += MB) {
    // K fragments direct from global (L2-resident)
    bf16x8 kf[4];
#pragma unroll
    for (int mt = 0; mt < 4; ++mt)
      kf[mt] = *(const bf16x8*)(Kh + ((size_t)b * N_ + m0 + mt * 16 + lm) * D_ + l4 * 8);

    __syncthreads();   // previous iter's Vt readers done
    {
      const f32x4* src = (const f32x4*)(vsrc_base + m0);
      f32x4* dst = (f32x4*)&Vt[vc][vh * 32];
#pragma unroll
      for (int i = 0; i < 4; ++i) dst[i] = src[i];
    }
    __syncthreads();

    // S = Q K^T : S[rt][mt] rows R0+rt*16+4*l4+reg, col m0+mt*16+lm
    f32x4 S[2][4];
#pragma unroll
    for (int rt = 0; rt < 2; ++rt)
#pragma unroll
      for (int mt = 0; mt < 4; ++mt)
        S[rt][mt] = __builtin_amdgcn_mfma_f32_16x16x32_bf16(qf[rt], kf[mt], z4, 0, 0, 0);

    // online softmax (row-reduce over 16 lanes via shfl_xor 1,2,4,8)
#pragma unroll
    for (int rt = 0; rt < 2; ++rt) {
      float sc[4];
#pragma unroll
      for (int r = 0; r < 4; ++r) {
        float v = fmaxf(fmaxf(S[rt][0][r], S[rt][1][r]), fmaxf(S[rt][2][r], S[rt][3][r]));
        v = fmaxf(v, __shfl_xor(v, 1));
        v = fmaxf(v, __shfl_xor(v, 2));
        v = fmaxf(v, __shfl_xor(v, 4));
        v = fmaxf(v, __shfl_xor(v, 8));
        float nm = fmaxf(m_run[rt][r], v);
        sc[r] = __expf(m_run[rt][r] - nm);
        m_run[rt][r] = nm;
      }
#pragma unroll
      for (int r = 0; r < 4; ++r) {
        float s = 0.f;
#pragma unroll
        for (int mt = 0; mt < 4; ++mt) {
          float p = __expf(S[rt][mt][r] - m_run[rt][r]);
          S[rt][mt][r] = p;
          s += p;
        }
        s += __shfl_xor(s, 1);
        s += __shfl_xor(s, 2);
        s += __shfl_xor(s, 4);
        s += __shfl_xor(s, 8);
        l_run[rt][r] = l_run[rt][r] * sc[r] + s;
      }
#pragma unroll
      for (int ct = 0; ct < 4; ++ct)
#pragma unroll
        for (int r = 0; r < 4; ++r)
          acc[rt][ct][r] *= sc[r];
      // P -> wave-private LDS (re-shape to A-fragment layout)
#pragma unroll
      for (int mt = 0; mt < 4; ++mt)
#pragma unroll
        for (int r = 0; r < 4; ++r)
          Pl[wid][rt * 16 + 4 * l4 + r][mt * 16 + lm] = (bf16_t)S[rt][mt][r];
    }

    // PV: acc[rt][ct] += P[32 x 64] * V^T[64 x 64]
#pragma unroll
    for (int kc = 0; kc < 2; ++kc) {
      bf16x8 pa[2];
#pragma unroll
      for (int rt = 0; rt < 2; ++rt)
        pa[rt] = *(const bf16x8*)&Pl[wid][rt * 16 + lm][kc * 32 + l4 * 8];
#pragma unroll
      for (int ct = 0; ct < 4; ++ct) {
        bf16x8 vf = *(const bf16x8*)&Vt[c0 + ct * 16 + lm][kc * 32 + l4 * 8];
#pragma unroll
        for (int rt = 0; rt < 2; ++rt)
          acc[rt][ct] = __builtin_amdgcn_mfma_f32_16x16x32_bf16(pa[rt], vf, acc[rt][ct], 0, 0, 0);
      }
    }
  }

  // epilogue: out = gamma * (acc / l) + x
  const float g = gamma[0];
#pragma unroll
  for (int rt = 0; rt < 2; ++rt) {
    float inv[4];
#pragma unroll
    for (int r = 0; r < 4; ++r) inv[r] = 1.f / l_run[rt][r];
#pragma unroll
    for (int ct = 0; ct < 4; ++ct) {
      int c = c0 + ct * 16 + lm;
#pragma unroll
      for (int r = 0; r < 4; ++r) {
        int n = R0 + rt * 16 + 4 * l4 + r;
        size_t idx = ((size_t)b * C_ + c) * (size_t)N_ + n;
        out[idx] = g * (acc[rt][ct][r] * inv[r]) + x[idx];
      }
    }
  }
}

extern "C" void kernel_launch(void* const* d_in, const int* in_sizes, int n_in,
                              void* d_out, int out_size, void* d_ws, size_t ws_size,
                              hipStream_t stream) {
  const float* x     = (const float*)d_in[0];
  const float* wq    = (const float*)d_in[1];
  const float* bq    = (const float*)d_in[2];
  const float* wk    = (const float*)d_in[3];
  const float* bk    = (const float*)d_in[4];
  const float* wv    = (const float*)d_in[5];
  const float* bv    = (const float*)d_in[6];
  const float* gamma = (const float*)d_in[7];
  float* out = (float*)d_out;

  // workspace layout: Qh 1MB | Kh 1MB | Vh 8MB  (10MB total)
  bf16_t* Qh = (bf16_t*)d_ws;
  bf16_t* Kh = Qh + (size_t)B_ * N_ * D_;
  bf16_t* Vh = Kh + (size_t)B_ * N_ * D_;

  proj_kernel<<<dim3(N_ / 64, 320 / 64, B_), 256, 0, stream>>>(
      x, wq, bq, wk, bk, wv, bv, Qh, Kh, Vh);
  attn_kernel<<<dim3(256), 512, 0, stream>>>(Qh, Kh, Vh, x, gamma, out);
}

// Round 2
// 155.676 us; speedup vs baseline: 2.4027x; 2.4027x over previous
//
#include <hip/hip_runtime.h>
#include <hip/hip_bf16.h>
#include <stdint.h>

#define B_ 4
#define C_ 256
#define N_ 4096
#define D_ 32

typedef __bf16 bf16_t;
typedef __bf16 bf16x4_t __attribute__((ext_vector_type(4)));
typedef __bf16 bf16x8_t __attribute__((ext_vector_type(8)));
typedef float  f32x4    __attribute__((ext_vector_type(4)));

__device__ __forceinline__ void gld_lds16(const void* g, void* l) {
  __builtin_amdgcn_global_load_lds((__attribute__((address_space(1))) void*)g,
                                   (__attribute__((address_space(3))) void*)l, 16, 0, 0);
}

// ---------------------------------------------------------------------------
// cast W (wq|wk|wv) -> Wb bf16 [320][256]
// ---------------------------------------------------------------------------
__global__ __launch_bounds__(256) void cast_w_kernel(
    const float* __restrict__ wq, const float* __restrict__ wk,
    const float* __restrict__ wv, bf16_t* __restrict__ Wb)
{
  const int gr = blockIdx.x;
  const int k  = threadIdx.x;
  float v;
  if (gr < 32)      v = wq[gr * C_ + k];
  else if (gr < 64) v = wk[(gr - 32) * C_ + k];
  else              v = wv[(gr - 64) * C_ + k];
  Wb[gr * C_ + k] = (bf16_t)v;
}

// ---------------------------------------------------------------------------
// cast + transpose x f32 [B][C][N] -> xbT bf16 [B][N][C]
// ---------------------------------------------------------------------------
__global__ __launch_bounds__(256) void cast_x_kernel(
    const float* __restrict__ x, bf16_t* __restrict__ xbT)
{
  __shared__ float xs[64][65];
  const int n0 = blockIdx.x * 64;
  const int c0 = blockIdx.y * 64;
  const int b  = blockIdx.z;
  const int t  = threadIdx.x;

  const int lr = t >> 4;
  const int lc = (t & 15) * 4;
#pragma unroll
  for (int i = 0; i < 4; ++i) {
    const f32x4 v = *(const f32x4*)(x + ((size_t)(b * C_ + c0 + lr + i * 16)) * N_ + n0 + lc);
    xs[lr + i * 16][lc + 0] = v[0];
    xs[lr + i * 16][lc + 1] = v[1];
    xs[lr + i * 16][lc + 2] = v[2];
    xs[lr + i * 16][lc + 3] = v[3];
  }
  __syncthreads();
  const int nr = t >> 2;
  const int cb = (t & 3) * 16;
  bf16_t tmp[16];
#pragma unroll
  for (int j = 0; j < 16; ++j) tmp[j] = (bf16_t)xs[cb + j][nr];
  bf16_t* dst = xbT + ((size_t)(b * N_ + n0 + nr)) * C_ + c0 + cb;
  *(bf16x8_t*)dst       = *(bf16x8_t*)&tmp[0];
  *(bf16x8_t*)(dst + 8) = *(bf16x8_t*)&tmp[8];
}

// ---------------------------------------------------------------------------
// Projection GEMM: Wb[320][256] x xbT^T -> Q/K/V, bf16 MFMA, no LDS
// (W and x tiles are L2-resident; af reused 4x, bf reused 5x per load).
// grid 256 = (b & 3, n-tile), block 256 = 4 waves, wave = 80 rows x 64 cols.
// ---------------------------------------------------------------------------
__global__ __launch_bounds__(256) void proj_kernel(
    const bf16_t* __restrict__ Wb, const bf16_t* __restrict__ xbT,
    const float* __restrict__ bq, const float* __restrict__ bk,
    const float* __restrict__ bv,
    bf16_t* __restrict__ Qh, bf16_t* __restrict__ Kh, bf16_t* __restrict__ Vh)
{
  const int bi = blockIdx.x;
  const int b  = bi & 3;
  const int n0 = (bi >> 2) * 64;
  const int t = threadIdx.x, w = t >> 6, lane = t & 63;
  const int l4 = lane >> 4, lm = lane & 15;

  const f32x4 z4 = {0.f, 0.f, 0.f, 0.f};
  f32x4 acc[5][4];
#pragma unroll
  for (int rt = 0; rt < 5; ++rt)
#pragma unroll
    for (int ct = 0; ct < 4; ++ct) acc[rt][ct] = z4;

#pragma unroll 1
  for (int k0 = 0; k0 < C_; k0 += 64) {
    bf16x8_t af[5][2], bfr[4][2];
#pragma unroll
    for (int rt = 0; rt < 5; ++rt)
#pragma unroll
      for (int kc = 0; kc < 2; ++kc)
        af[rt][kc] = *(const bf16x8_t*)(Wb + (size_t)(w * 80 + rt * 16 + lm) * C_ + k0 + kc * 32 + l4 * 8);
#pragma unroll
    for (int ct = 0; ct < 4; ++ct)
#pragma unroll
      for (int kc = 0; kc < 2; ++kc)
        bfr[ct][kc] = *(const bf16x8_t*)(xbT + ((size_t)(b * N_ + n0 + ct * 16 + lm)) * C_ + k0 + kc * 32 + l4 * 8);
#pragma unroll
    for (int rt = 0; rt < 5; ++rt)
#pragma unroll
      for (int ct = 0; ct < 4; ++ct)
#pragma unroll
        for (int kc = 0; kc < 2; ++kc)
          acc[rt][ct] = __builtin_amdgcn_mfma_f32_16x16x32_bf16(af[rt][kc], bfr[ct][kc], acc[rt][ct], 0, 0, 0);
  }

#pragma unroll
  for (int rt = 0; rt < 5; ++rt)
#pragma unroll
    for (int r = 0; r < 4; ++r) {
      const int gr = w * 80 + rt * 16 + 4 * l4 + r;
      const float bias = (gr < 32) ? bq[gr] : (gr < 64) ? bk[gr - 32] : bv[gr - 64];
#pragma unroll
      for (int ct = 0; ct < 4; ++ct) {
        const int n = n0 + ct * 16 + lm;
        const float v = acc[rt][ct][r] + bias;
        if (gr < 32)      Qh[((size_t)(b * N_ + n)) * D_ + gr] = (bf16_t)v;
        else if (gr < 64) Kh[((size_t)(b * N_ + n)) * D_ + (gr - 32)] = (bf16_t)v;
        else              Vh[((size_t)(b * C_ + (gr - 64))) * N_ + n] = (bf16_t)v;
      }
    }
}

// ---------------------------------------------------------------------------
// Flash attention, swapped-operand MFMA.
// 256 blocks x 8 waves. Block = 64 q-rows x 256 ch; wave = 32 rows x 64 ch.
// S^T = mfma(K,Q): lane owns q-row lm -> lane-local softmax (+2 shfl_xor).
// PV  = mfma(V,P): out cols = q -> rescale/div lane-local, coalesced stores.
// V triple-buffered in LDS via global_load_lds, XOR-swizzled via source addr.
// ---------------------------------------------------------------------------
__global__ __launch_bounds__(512, 1) void attn_kernel(
    const bf16_t* __restrict__ Qh, const bf16_t* __restrict__ Kh,
    const bf16_t* __restrict__ Vh, const float* __restrict__ x,
    const float* __restrict__ gamma, float* __restrict__ out)
{
  __shared__ __align__(16) bf16_t Vt[3][C_][64];   // 96 KB
  __shared__ __align__(16) bf16_t Pl[8][32][64];   // 32 KB, wave-private

  const int bi = blockIdx.x;
  const int xcd = bi & 7, slot = bi >> 3;
  const int b  = xcd >> 1;                 // 2 XCDs per batch -> K,V L2-resident
  const int q0 = ((xcd & 1) * 32 + slot) * 64;

  const int t = threadIdx.x, wid = t >> 6, lane = t & 63;
  const int l4 = lane >> 4, lm = lane & 15;
  const int rh = wid & 1, cg = wid >> 1;
  const int pswz = (lm & 7) << 3;          // element-XOR swizzle (P and Vt reads)

  const f32x4 z4 = {0.f, 0.f, 0.f, 0.f};

  bf16x8_t qf[2];
#pragma unroll
  for (int rt2 = 0; rt2 < 2; ++rt2)
    qf[rt2] = *(const bf16x8_t*)(Qh + ((size_t)(b * N_ + q0 + rh * 32 + rt2 * 16 + lm)) * D_ + l4 * 8);

  f32x4 acc[2][4];
#pragma unroll
  for (int rt2 = 0; rt2 < 2; ++rt2)
#pragma unroll
    for (int ct = 0; ct < 4; ++ct) acc[rt2][ct] = z4;
  float m_run[2] = {-1e30f, -1e30f}, l_run[2] = {0.f, 0.f};

  // V staging: per wave 4 instrs x (8 rows x 128B); swizzle via global source.
  const int vr  = lane >> 3;
  const int msw = ((lane & 7) ^ vr) << 3;
  const bf16_t* vsrc[4];
#pragma unroll
  for (int u = 0; u < 4; ++u)
    vsrc[u] = Vh + ((size_t)(b * C_ + wid * 32 + u * 8 + vr)) * N_ + msw;

  const bf16_t* kbase = Kh + ((size_t)b * N_ + lm) * D_ + l4 * 8;

  // prologue: stage tile 0, load K tile 0
#pragma unroll
  for (int u = 0; u < 4; ++u)
    gld_lds16(vsrc[u], &Vt[0][wid * 32 + u * 8][0]);
  bf16x8_t kf[4], kn[4];
#pragma unroll
  for (int mt = 0; mt < 4; ++mt)
    kf[mt] = *(const bf16x8_t*)(kbase + (size_t)(mt * 16) * D_);

  int cur = 0;
#pragma unroll 1
  for (int it = 0; it < N_ / 64; ++it) {
    const int m0n = ((it + 1) & 63) * 64;
#pragma unroll
    for (int mt = 0; mt < 4; ++mt)
      kn[mt] = *(const bf16x8_t*)(kbase + (size_t)(m0n + mt * 16) * D_);

    // S^T[m][q]
    f32x4 S[2][4];
#pragma unroll
    for (int rt2 = 0; rt2 < 2; ++rt2)
#pragma unroll
      for (int mt = 0; mt < 4; ++mt)
        S[rt2][mt] = __builtin_amdgcn_mfma_f32_16x16x32_bf16(kf[mt], qf[rt2], z4, 0, 0, 0);

    // online softmax: lane owns q-row lm (per rt2); 16 local vals + 2 shfls
    float sc[2]; int chg[2];
#pragma unroll
    for (int rt2 = 0; rt2 < 2; ++rt2) {
      float vm = S[rt2][0][0];
#pragma unroll
      for (int mt = 0; mt < 4; ++mt)
#pragma unroll
        for (int r = 0; r < 4; ++r) vm = fmaxf(vm, S[rt2][mt][r]);
      vm = fmaxf(vm, __shfl_xor(vm, 16));
      vm = fmaxf(vm, __shfl_xor(vm, 32));
      const float mo = m_run[rt2];
      const float nm = fmaxf(mo, vm);
      chg[rt2] = vm > mo;
      sc[rt2]  = __expf(mo - nm);
      m_run[rt2] = nm;
      float s = 0.f;
      const int prow = rt2 * 16 + lm;
#pragma unroll
      for (int mt = 0; mt < 4; ++mt) {
        const float p0 = __expf(S[rt2][mt][0] - nm);
        const float p1 = __expf(S[rt2][mt][1] - nm);
        const float p2 = __expf(S[rt2][mt][2] - nm);
        const float p3 = __expf(S[rt2][mt][3] - nm);
        s += (p0 + p1) + (p2 + p3);
        bf16x4_t wv4 = {(bf16_t)p0, (bf16_t)p1, (bf16_t)p2, (bf16_t)p3};
        *(bf16x4_t*)&Pl[wid][prow][(16 * mt + 4 * l4) ^ pswz] = wv4;
      }
      s += __shfl_xor(s, 16);
      s += __shfl_xor(s, 32);
      l_run[rt2] = l_run[rt2] * sc[rt2] + s;
    }
    if (__any(chg[0] || chg[1])) {
#pragma unroll
      for (int rt2 = 0; rt2 < 2; ++rt2)
#pragma unroll
        for (int ct = 0; ct < 4; ++ct) acc[rt2][ct] *= sc[rt2];
    }

    __syncthreads();   // V tile `cur` fully landed (compiler drains vmcnt)

    // stage tile it+1 into buf bn (in flight until next barrier)
    const int bn = (cur == 2) ? 0 : cur + 1;
#pragma unroll
    for (int u = 0; u < 4; ++u)
      gld_lds16(vsrc[u] + m0n, &Vt[bn][wid * 32 + u * 8][0]);

    // PV: acc[c][q] += V[c][m] * P[m][q]
    bf16x8_t pa[2][2];
#pragma unroll
    for (int rt2 = 0; rt2 < 2; ++rt2)
#pragma unroll
      for (int kc = 0; kc < 2; ++kc)
        pa[rt2][kc] = *(const bf16x8_t*)&Pl[wid][rt2 * 16 + lm][(32 * kc + 8 * l4) ^ pswz];
#pragma unroll
    for (int ct = 0; ct < 4; ++ct) {
#pragma unroll
      for (int kc = 0; kc < 2; ++kc) {
        const bf16x8_t vf = *(const bf16x8_t*)&Vt[cur][cg * 64 + ct * 16 + lm][(32 * kc + 8 * l4) ^ pswz];
#pragma unroll
        for (int rt2 = 0; rt2 < 2; ++rt2)
          acc[rt2][ct] = __builtin_amdgcn_mfma_f32_16x16x32_bf16(vf, pa[rt2][kc], acc[rt2][ct], 0, 0, 0);
      }
    }

#pragma unroll
    for (int mt = 0; mt < 4; ++mt) kf[mt] = kn[mt];
    cur = bn;
  }

  // epilogue: out = gamma*acc/l + x ; cols = q -> 64B-coalesced runs
  const float g = gamma[0];
  const int n = q0 + rh * 32 + lm;
#pragma unroll
  for (int rt2 = 0; rt2 < 2; ++rt2) {
    const float inv = 1.f / l_run[rt2];
#pragma unroll
    for (int ct = 0; ct < 4; ++ct) {
#pragma unroll
      for (int r = 0; r < 4; ++r) {
        const int c = cg * 64 + ct * 16 + 4 * l4 + r;
        const size_t idx = ((size_t)(b * C_ + c)) * N_ + n + rt2 * 16;
        out[idx] = g * (acc[rt2][ct][r] * inv) + x[idx];
      }
    }
  }
}

extern "C" void kernel_launch(void* const* d_in, const int* in_sizes, int n_in,
                              void* d_out, int out_size, void* d_ws, size_t ws_size,
                              hipStream_t stream) {
  const float* x     = (const float*)d_in[0];
  const float* wq    = (const float*)d_in[1];
  const float* bq    = (const float*)d_in[2];
  const float* wk    = (const float*)d_in[3];
  const float* bk    = (const float*)d_in[4];
  const float* wv    = (const float*)d_in[5];
  const float* bv    = (const float*)d_in[6];
  const float* gamma = (const float*)d_in[7];
  float* out = (float*)d_out;

  // ws: Qh 1MB | Kh 1MB | Vh 8MB | Wb 160KB | xbT 8MB  (~18.2MB)
  bf16_t* Qh  = (bf16_t*)d_ws;
  bf16_t* Kh  = Qh + (size_t)B_ * N_ * D_;
  bf16_t* Vh  = Kh + (size_t)B_ * N_ * D_;
  bf16_t* Wb  = Vh + (size_t)B_ * C_ * N_;
  bf16_t* xbT = Wb + (size_t)320 * C_;

  cast_w_kernel<<<320, 256, 0, stream>>>(wq, wk, wv, Wb);
  cast_x_kernel<<<dim3(64, 4, 4), 256, 0, stream>>>(x, xbT);
  proj_kernel<<<256, 256, 0, stream>>>(Wb, xbT, bq, bk, bv, Qh, Kh, Vh);
  attn_kernel<<<256, 512, 0, stream>>>(Qh, Kh, Vh, x, gamma, out);
}

// Round 3
// 115.611 us; speedup vs baseline: 3.2354x; 1.3466x over previous
//
#include <hip/hip_runtime.h>
#include <hip/hip_bf16.h>
#include <stdint.h>

#define B_ 4
#define C_ 256
#define N_ 4096
#define D_ 32
#define KT 256   // keys per outer iteration

typedef __bf16 bf16_t;
typedef __bf16 bf16x4_t __attribute__((ext_vector_type(4)));
typedef __bf16 bf16x8_t __attribute__((ext_vector_type(8)));
typedef float  f32x4    __attribute__((ext_vector_type(4)));

__device__ __forceinline__ void gld_lds16(const void* g, void* l) {
  __builtin_amdgcn_global_load_lds((__attribute__((address_space(1))) void*)g,
                                   (__attribute__((address_space(3))) void*)l, 16, 0, 0);
}

// ---------------------------------------------------------------------------
// cast W (wq|wk|wv) -> Wb bf16 [320][256]
// ---------------------------------------------------------------------------
__global__ __launch_bounds__(256) void cast_w_kernel(
    const float* __restrict__ wq, const float* __restrict__ wk,
    const float* __restrict__ wv, bf16_t* __restrict__ Wb)
{
  const int gr = blockIdx.x;
  const int k  = threadIdx.x;
  float v;
  if (gr < 32)      v = wq[gr * C_ + k];
  else if (gr < 64) v = wk[(gr - 32) * C_ + k];
  else              v = wv[(gr - 64) * C_ + k];
  Wb[gr * C_ + k] = (bf16_t)v;
}

// ---------------------------------------------------------------------------
// cast + transpose x f32 [B][C][N] -> xbT bf16 [B][N][C]
// ---------------------------------------------------------------------------
__global__ __launch_bounds__(256) void cast_x_kernel(
    const float* __restrict__ x, bf16_t* __restrict__ xbT)
{
  __shared__ float xs[64][65];
  const int n0 = blockIdx.x * 64;
  const int c0 = blockIdx.y * 64;
  const int b  = blockIdx.z;
  const int t  = threadIdx.x;

  const int lr = t >> 4;
  const int lc = (t & 15) * 4;
#pragma unroll
  for (int i = 0; i < 4; ++i) {
    const f32x4 v = *(const f32x4*)(x + ((size_t)(b * C_ + c0 + lr + i * 16)) * N_ + n0 + lc);
    xs[lr + i * 16][lc + 0] = v[0];
    xs[lr + i * 16][lc + 1] = v[1];
    xs[lr + i * 16][lc + 2] = v[2];
    xs[lr + i * 16][lc + 3] = v[3];
  }
  __syncthreads();
  const int nr = t >> 2;
  const int cb = (t & 3) * 16;
  bf16_t tmp[16];
#pragma unroll
  for (int j = 0; j < 16; ++j) tmp[j] = (bf16_t)xs[cb + j][nr];
  bf16_t* dst = xbT + ((size_t)(b * N_ + n0 + nr)) * C_ + c0 + cb;
  *(bf16x8_t*)dst       = *(bf16x8_t*)&tmp[0];
  *(bf16x8_t*)(dst + 8) = *(bf16x8_t*)&tmp[8];
}

// ---------------------------------------------------------------------------
// Projection GEMM: Wb[320][256] x xbT^T -> Q/K/V bf16 MFMA, no LDS.
// Q rows are pre-scaled by log2(e) so attention softmax runs in exp2 domain.
// ---------------------------------------------------------------------------
__global__ __launch_bounds__(256) void proj_kernel(
    const bf16_t* __restrict__ Wb, const bf16_t* __restrict__ xbT,
    const float* __restrict__ bq, const float* __restrict__ bk,
    const float* __restrict__ bv,
    bf16_t* __restrict__ Qh, bf16_t* __restrict__ Kh, bf16_t* __restrict__ Vh)
{
  const int bi = blockIdx.x;
  const int b  = bi & 3;
  const int n0 = (bi >> 2) * 64;
  const int t = threadIdx.x, w = t >> 6, lane = t & 63;
  const int l4 = lane >> 4, lm = lane & 15;

  const f32x4 z4 = {0.f, 0.f, 0.f, 0.f};
  f32x4 acc[5][4];
#pragma unroll
  for (int rt = 0; rt < 5; ++rt)
#pragma unroll
    for (int ct = 0; ct < 4; ++ct) acc[rt][ct] = z4;

#pragma unroll 1
  for (int k0 = 0; k0 < C_; k0 += 64) {
    bf16x8_t af[5][2], bfr[4][2];
#pragma unroll
    for (int rt = 0; rt < 5; ++rt)
#pragma unroll
      for (int kc = 0; kc < 2; ++kc)
        af[rt][kc] = *(const bf16x8_t*)(Wb + (size_t)(w * 80 + rt * 16 + lm) * C_ + k0 + kc * 32 + l4 * 8);
#pragma unroll
    for (int ct = 0; ct < 4; ++ct)
#pragma unroll
      for (int kc = 0; kc < 2; ++kc)
        bfr[ct][kc] = *(const bf16x8_t*)(xbT + ((size_t)(b * N_ + n0 + ct * 16 + lm)) * C_ + k0 + kc * 32 + l4 * 8);
#pragma unroll
    for (int rt = 0; rt < 5; ++rt)
#pragma unroll
      for (int ct = 0; ct < 4; ++ct)
#pragma unroll
        for (int kc = 0; kc < 2; ++kc)
          acc[rt][ct] = __builtin_amdgcn_mfma_f32_16x16x32_bf16(af[rt][kc], bfr[ct][kc], acc[rt][ct], 0, 0, 0);
  }

#pragma unroll
  for (int rt = 0; rt < 5; ++rt)
#pragma unroll
    for (int r = 0; r < 4; ++r) {
      const int gr = w * 80 + rt * 16 + 4 * l4 + r;
      const float bias = (gr < 32) ? bq[gr] : (gr < 64) ? bk[gr - 32] : bv[gr - 64];
#pragma unroll
      for (int ct = 0; ct < 4; ++ct) {
        const int n = n0 + ct * 16 + lm;
        float v = acc[rt][ct][r] + bias;
        if (gr < 32) {
          v *= 1.44269504088896f;   // fold log2(e) into Q -> exp2-domain softmax
          Qh[((size_t)(b * N_ + n)) * D_ + gr] = (bf16_t)v;
        } else if (gr < 64) {
          Kh[((size_t)(b * N_ + n)) * D_ + (gr - 32)] = (bf16_t)v;
        } else {
          Vh[((size_t)(b * C_ + (gr - 64))) * N_ + n] = (bf16_t)v;
        }
      }
    }
}

// ---------------------------------------------------------------------------
// Flash attention, KT=256 key tile, ZERO softmax redundancy:
// 8 waves = (rh 0..1) x (cg 0..3). Wave (rh,cg) computes S/softmax for its
// 32 q-rows x 64-key QUARTER (distinct work), P shared via LDS; per-row
// max/sum combined across quarters through tiny PM/PS buffers (2 barriers).
// PV consumes all 256 keys in 4 sub-steps with double-buffered V staging.
// ---------------------------------------------------------------------------
__global__ __launch_bounds__(512, 2) void attn_kernel(
    const bf16_t* __restrict__ Qh, const bf16_t* __restrict__ Kh,
    const bf16_t* __restrict__ Vh, const float* __restrict__ x,
    const float* __restrict__ gamma, float* __restrict__ out)
{
  __shared__ __align__(16) bf16_t Vt[2][C_][64];    // 64 KB, double-buffered V
  __shared__ __align__(16) bf16_t Pl[2][32][KT];    // 32 KB, P[q-local][key-local]
  __shared__ __align__(16) float  PMx[2][64][4];    // per-row partial max, per quarter
  __shared__ __align__(16) float  PSx[2][64][4];    // per-row partial sum

  const int bi = blockIdx.x;
  const int xcd = bi & 7, slot = bi >> 3;
  const int b  = xcd >> 1;                 // 2 XCDs per batch -> K,V L2-resident
  const int q0 = ((xcd & 1) * 32 + slot) * 64;

  const int t = threadIdx.x, wid = t >> 6, lane = t & 63;
  const int l4 = lane >> 4, lm = lane & 15;
  const int rh = wid & 1, cg = wid >> 1;
  const int pswz = (lm & 7) << 3;

  const f32x4 z4 = {0.f, 0.f, 0.f, 0.f};

  // --- V staging sources (swizzle folded into global address) ---
  const int vr  = lane >> 3;
  const int msw = ((lane & 7) ^ vr) << 3;
  const bf16_t* vsrc[4];
#pragma unroll
  for (int u = 0; u < 4; ++u)
    vsrc[u] = Vh + ((size_t)(b * C_ + 32 * wid + 8 * u + vr)) * N_ + msw;
#pragma unroll
  for (int u = 0; u < 4; ++u)
    gld_lds16(vsrc[u], &Vt[0][32 * wid + 8 * u][0]);

  // --- K quarter base + first tile ---
  const bf16_t* kbase = Kh + ((size_t)(b * N_ + cg * 64 + lm)) * D_ + l4 * 8;
  bf16x8_t kf[4], kn[4];
#pragma unroll
  for (int mt = 0; mt < 4; ++mt)
    kf[mt] = *(const bf16x8_t*)(kbase + (size_t)(mt * 16) * D_);

  // --- Q fragments (held whole kernel) ---
  bf16x8_t qf[2];
#pragma unroll
  for (int rt2 = 0; rt2 < 2; ++rt2)
    qf[rt2] = *(const bf16x8_t*)(Qh + ((size_t)(b * N_ + q0 + rh * 32 + rt2 * 16 + lm)) * D_ + l4 * 8);

  f32x4 acc[2][4];
#pragma unroll
  for (int rt2 = 0; rt2 < 2; ++rt2)
#pragma unroll
    for (int ct = 0; ct < 4; ++ct) acc[rt2][ct] = z4;
  float m_run[2] = {-1e30f, -1e30f}, l_run[2] = {0.f, 0.f};

  int cur = 0;
#pragma unroll 1
  for (int it = 0; it < N_ / KT; ++it) {
    // ---- S quarter: 32 q-rows x 64 keys (distinct per wave) ----
    f32x4 S[2][4];
#pragma unroll
    for (int rt2 = 0; rt2 < 2; ++rt2)
#pragma unroll
      for (int mt = 0; mt < 4; ++mt)
        S[rt2][mt] = __builtin_amdgcn_mfma_f32_16x16x32_bf16(kf[mt], qf[rt2], z4, 0, 0, 0);

    // prefetch next K quarter (consumed next outer iter)
    const int k0n = ((it + 1) * KT) & (N_ - 1);
#pragma unroll
    for (int mt = 0; mt < 4; ++mt)
      kn[mt] = *(const bf16x8_t*)(kbase + (size_t)(k0n + mt * 16) * D_);

    // ---- per-row partial max over this quarter ----
    float pmx[2];
#pragma unroll
    for (int rt2 = 0; rt2 < 2; ++rt2) {
      float a0 = fmaxf(fmaxf(S[rt2][0][0], S[rt2][0][1]), fmaxf(S[rt2][0][2], S[rt2][0][3]));
      float a1 = fmaxf(fmaxf(S[rt2][1][0], S[rt2][1][1]), fmaxf(S[rt2][1][2], S[rt2][1][3]));
      float a2 = fmaxf(fmaxf(S[rt2][2][0], S[rt2][2][1]), fmaxf(S[rt2][2][2], S[rt2][2][3]));
      float a3 = fmaxf(fmaxf(S[rt2][3][0], S[rt2][3][1]), fmaxf(S[rt2][3][2], S[rt2][3][3]));
      float v = fmaxf(fmaxf(a0, a1), fmaxf(a2, a3));
      v = fmaxf(v, __shfl_xor(v, 16));
      v = fmaxf(v, __shfl_xor(v, 32));
      pmx[rt2] = v;
    }
    if (lane < 32) PMx[rh][lane][cg] = (lane < 16) ? pmx[0] : pmx[1];
    __syncthreads();   // B1: partial maxes visible

    // ---- combine maxes, rescale factor ----
    float sc[2], nm[2]; int chg[2];
#pragma unroll
    for (int rt2 = 0; rt2 < 2; ++rt2) {
      const f32x4 pv = *(const f32x4*)&PMx[rh][rt2 * 16 + lm][0];
      const float tm = fmaxf(fmaxf(pv[0], pv[1]), fmaxf(pv[2], pv[3]));
      const float mo = m_run[rt2];
      nm[rt2]  = fmaxf(mo, tm);
      chg[rt2] = tm > mo;
      sc[rt2]  = __builtin_amdgcn_exp2f(mo - nm[rt2]);
      m_run[rt2] = nm[rt2];
    }

    // ---- exp2, P writes (own quarter), partial sums ----
    float psx[2];
#pragma unroll
    for (int rt2 = 0; rt2 < 2; ++rt2) {
      float s = 0.f;
      const int prow = rt2 * 16 + lm;
#pragma unroll
      for (int mt = 0; mt < 4; ++mt) {
        const float p0 = __builtin_amdgcn_exp2f(S[rt2][mt][0] - nm[rt2]);
        const float p1 = __builtin_amdgcn_exp2f(S[rt2][mt][1] - nm[rt2]);
        const float p2 = __builtin_amdgcn_exp2f(S[rt2][mt][2] - nm[rt2]);
        const float p3 = __builtin_amdgcn_exp2f(S[rt2][mt][3] - nm[rt2]);
        s += (p0 + p1) + (p2 + p3);
        bf16x4_t w4 = {(bf16_t)p0, (bf16_t)p1, (bf16_t)p2, (bf16_t)p3};
        *(bf16x4_t*)&Pl[rh][prow][(cg * 64 + 16 * mt + 4 * l4) ^ pswz] = w4;
      }
      s += __shfl_xor(s, 16);
      s += __shfl_xor(s, 32);
      psx[rt2] = s;
    }
    if (lane < 32) PSx[rh][lane][cg] = (lane < 16) ? psx[0] : psx[1];

    // rescale accumulator (skip when no row max grew)
    if (__any(chg[0] || chg[1])) {
#pragma unroll
      for (int rt2 = 0; rt2 < 2; ++rt2)
#pragma unroll
        for (int ct = 0; ct < 4; ++ct) acc[rt2][ct] *= sc[rt2];
    }
    __syncthreads();   // B2: P + partial sums visible

    // ---- l update ----
#pragma unroll
    for (int rt2 = 0; rt2 < 2; ++rt2) {
      const f32x4 sv = *(const f32x4*)&PSx[rh][rt2 * 16 + lm][0];
      l_run[rt2] = l_run[rt2] * sc[rt2] + ((sv[0] + sv[1]) + (sv[2] + sv[3]));
    }

    // ---- PV over 256 keys in 4 sub-steps (double-buffered V) ----
#pragma unroll 1
    for (int s4 = 0; s4 < 4; ++s4) {
      const int knx = (it * KT + (s4 + 1) * 64) & (N_ - 1);
#pragma unroll
      for (int u = 0; u < 4; ++u)
        gld_lds16(vsrc[u] + knx, &Vt[cur ^ 1][32 * wid + 8 * u][0]);

      bf16x8_t pa[2][2];
#pragma unroll
      for (int rt2 = 0; rt2 < 2; ++rt2)
#pragma unroll
        for (int kc = 0; kc < 2; ++kc)
          pa[rt2][kc] = *(const bf16x8_t*)&Pl[rh][rt2 * 16 + lm][(s4 * 64 + kc * 32 + 8 * l4) ^ pswz];
#pragma unroll
      for (int ct = 0; ct < 4; ++ct) {
#pragma unroll
        for (int kc = 0; kc < 2; ++kc) {
          const bf16x8_t vf = *(const bf16x8_t*)&Vt[cur][cg * 64 + ct * 16 + lm][(kc * 32 + 8 * l4) ^ pswz];
#pragma unroll
          for (int rt2 = 0; rt2 < 2; ++rt2)
            acc[rt2][ct] = __builtin_amdgcn_mfma_f32_16x16x32_bf16(vf, pa[rt2][kc], acc[rt2][ct], 0, 0, 0);
        }
      }
      __syncthreads();
      cur ^= 1;
    }

#pragma unroll
    for (int mt = 0; mt < 4; ++mt) kf[mt] = kn[mt];
  }

  // ---- epilogue: out = gamma*acc/l + x (64B-coalesced runs) ----
  const float g = gamma[0];
  const int n = q0 + rh * 32 + lm;
#pragma unroll
  for (int rt2 = 0; rt2 < 2; ++rt2) {
    const float inv = 1.f / l_run[rt2];
#pragma unroll
    for (int ct = 0; ct < 4; ++ct) {
#pragma unroll
      for (int r = 0; r < 4; ++r) {
        const int c = cg * 64 + ct * 16 + 4 * l4 + r;
        const size_t idx = ((size_t)(b * C_ + c)) * N_ + n + rt2 * 16;
        out[idx] = g * (acc[rt2][ct][r] * inv) + x[idx];
      }
    }
  }
}

extern "C" void kernel_launch(void* const* d_in, const int* in_sizes, int n_in,
                              void* d_out, int out_size, void* d_ws, size_t ws_size,
                              hipStream_t stream) {
  const float* x     = (const float*)d_in[0];
  const float* wq    = (const float*)d_in[1];
  const float* bq    = (const float*)d_in[2];
  const float* wk    = (const float*)d_in[3];
  const float* bk    = (const float*)d_in[4];
  const float* wv    = (const float*)d_in[5];
  const float* bv    = (const float*)d_in[6];
  const float* gamma = (const float*)d_in[7];
  float* out = (float*)d_out;

  // ws: Qh 1MB | Kh 1MB | Vh 8MB | Wb 160KB | xbT 8MB  (~18.2MB)
  bf16_t* Qh  = (bf16_t*)d_ws;
  bf16_t* Kh  = Qh + (size_t)B_ * N_ * D_;
  bf16_t* Vh  = Kh + (size_t)B_ * N_ * D_;
  bf16_t* Wb  = Vh + (size_t)B_ * C_ * N_;
  bf16_t* xbT = Wb + (size_t)320 * C_;

  cast_w_kernel<<<320, 256, 0, stream>>>(wq, wk, wv, Wb);
  cast_x_kernel<<<dim3(64, 4, 4), 256, 0, stream>>>(x, xbT);
  proj_kernel<<<256, 256, 0, stream>>>(Wb, xbT, bq, bk, bv, Qh, Kh, Vh);
  attn_kernel<<<256, 512, 0, stream>>>(Qh, Kh, Vh, x, gamma, out);
}

// Round 4
// 114.581 us; speedup vs baseline: 3.2645x; 1.0090x over previous
//
#include <hip/hip_runtime.h>
#include <hip/hip_bf16.h>
#include <stdint.h>

#define B_ 4
#define C_ 256
#define N_ 4096
#define D_ 32
#define KT 256   // keys per outer iteration (softmax tile)

typedef __bf16 bf16_t;
typedef __bf16 bf16x4_t __attribute__((ext_vector_type(4)));
typedef __bf16 bf16x8_t __attribute__((ext_vector_type(8)));
typedef float  f32x4    __attribute__((ext_vector_type(4)));

__device__ __forceinline__ void gld_lds16(const void* g, void* l) {
  __builtin_amdgcn_global_load_lds((__attribute__((address_space(1))) void*)g,
                                   (__attribute__((address_space(3))) void*)l, 16, 0, 0);
}

// ---------------------------------------------------------------------------
// fused cast: blocks <1024 transpose+cast x -> xbT bf16 [B][N][C];
// blocks >=1024 cast W (wq|wk|wv) -> Wb bf16 [320][256]
// ---------------------------------------------------------------------------
__global__ __launch_bounds__(256) void cast_kernel(
    const float* __restrict__ x,
    const float* __restrict__ wq, const float* __restrict__ wk,
    const float* __restrict__ wv,
    bf16_t* __restrict__ xbT, bf16_t* __restrict__ Wb)
{
  const int bid = blockIdx.x;
  const int t = threadIdx.x;
  if (bid >= 1024) {
    const int gr = bid - 1024;   // 0..319
    float v;
    if (gr < 32)      v = wq[gr * C_ + t];
    else if (gr < 64) v = wk[(gr - 32) * C_ + t];
    else              v = wv[(gr - 64) * C_ + t];
    Wb[gr * C_ + t] = (bf16_t)v;
    return;
  }
  __shared__ float xs[64][65];
  const int n0 = (bid & 63) * 64;
  const int c0 = ((bid >> 6) & 3) * 64;
  const int b  = bid >> 8;

  const int lr = t >> 4;
  const int lc = (t & 15) * 4;
#pragma unroll
  for (int i = 0; i < 4; ++i) {
    const f32x4 v = *(const f32x4*)(x + ((size_t)(b * C_ + c0 + lr + i * 16)) * N_ + n0 + lc);
    xs[lr + i * 16][lc + 0] = v[0];
    xs[lr + i * 16][lc + 1] = v[1];
    xs[lr + i * 16][lc + 2] = v[2];
    xs[lr + i * 16][lc + 3] = v[3];
  }
  __syncthreads();
  const int nr = t >> 2;
  const int cb = (t & 3) * 16;
  bf16_t tmp[16];
#pragma unroll
  for (int j = 0; j < 16; ++j) tmp[j] = (bf16_t)xs[cb + j][nr];
  bf16_t* dst = xbT + ((size_t)(b * N_ + n0 + nr)) * C_ + c0 + cb;
  *(bf16x8_t*)dst       = *(bf16x8_t*)&tmp[0];
  *(bf16x8_t*)(dst + 8) = *(bf16x8_t*)&tmp[8];
}

// ---------------------------------------------------------------------------
// Projection GEMM: Wb[320][256] x xbT^T -> Q/K/V bf16 MFMA, no LDS.
// Q rows pre-scaled by log2(e) so attention softmax runs in exp2 domain.
// ---------------------------------------------------------------------------
__global__ __launch_bounds__(256) void proj_kernel(
    const bf16_t* __restrict__ Wb, const bf16_t* __restrict__ xbT,
    const float* __restrict__ bq, const float* __restrict__ bk,
    const float* __restrict__ bv,
    bf16_t* __restrict__ Qh, bf16_t* __restrict__ Kh, bf16_t* __restrict__ Vh)
{
  const int bi = blockIdx.x;
  const int b  = bi & 3;
  const int n0 = (bi >> 2) * 64;
  const int t = threadIdx.x, w = t >> 6, lane = t & 63;
  const int l4 = lane >> 4, lm = lane & 15;

  const f32x4 z4 = {0.f, 0.f, 0.f, 0.f};
  f32x4 acc[5][4];
#pragma unroll
  for (int rt = 0; rt < 5; ++rt)
#pragma unroll
    for (int ct = 0; ct < 4; ++ct) acc[rt][ct] = z4;

#pragma unroll 1
  for (int k0 = 0; k0 < C_; k0 += 64) {
    bf16x8_t af[5][2], bfr[4][2];
#pragma unroll
    for (int rt = 0; rt < 5; ++rt)
#pragma unroll
      for (int kc = 0; kc < 2; ++kc)
        af[rt][kc] = *(const bf16x8_t*)(Wb + (size_t)(w * 80 + rt * 16 + lm) * C_ + k0 + kc * 32 + l4 * 8);
#pragma unroll
    for (int ct = 0; ct < 4; ++ct)
#pragma unroll
      for (int kc = 0; kc < 2; ++kc)
        bfr[ct][kc] = *(const bf16x8_t*)(xbT + ((size_t)(b * N_ + n0 + ct * 16 + lm)) * C_ + k0 + kc * 32 + l4 * 8);
#pragma unroll
    for (int rt = 0; rt < 5; ++rt)
#pragma unroll
      for (int ct = 0; ct < 4; ++ct)
#pragma unroll
        for (int kc = 0; kc < 2; ++kc)
          acc[rt][ct] = __builtin_amdgcn_mfma_f32_16x16x32_bf16(af[rt][kc], bfr[ct][kc], acc[rt][ct], 0, 0, 0);
  }

#pragma unroll
  for (int rt = 0; rt < 5; ++rt)
#pragma unroll
    for (int r = 0; r < 4; ++r) {
      const int gr = w * 80 + rt * 16 + 4 * l4 + r;
      const float bias = (gr < 32) ? bq[gr] : (gr < 64) ? bk[gr - 32] : bv[gr - 64];
#pragma unroll
      for (int ct = 0; ct < 4; ++ct) {
        const int n = n0 + ct * 16 + lm;
        float v = acc[rt][ct][r] + bias;
        if (gr < 32) {
          v *= 1.44269504088896f;
          Qh[((size_t)(b * N_ + n)) * D_ + gr] = (bf16_t)v;
        } else if (gr < 64) {
          Kh[((size_t)(b * N_ + n)) * D_ + (gr - 32)] = (bf16_t)v;
        } else {
          Vh[((size_t)(b * C_ + (gr - 64))) * N_ + n] = (bf16_t)v;
        }
      }
    }
}

// ---------------------------------------------------------------------------
// Flash attention, KT=256, zero softmax redundancy, MANUAL SYNC:
//  - softmax barriers: s_waitcnt lgkmcnt(0) + s_barrier (DMA stays in flight)
//  - PV substeps: triple-buffered V, counted s_waitcnt vmcnt(4) + s_barrier
//    (stage substep s+2 while computing s; never drain vmcnt in PV)
// ---------------------------------------------------------------------------
__global__ __launch_bounds__(512, 2) void attn_kernel(
    const bf16_t* __restrict__ Qh, const bf16_t* __restrict__ Kh,
    const bf16_t* __restrict__ Vh, const float* __restrict__ x,
    const float* __restrict__ gamma, float* __restrict__ out)
{
  __shared__ __align__(16) bf16_t Vt[3][C_][64];    // 96 KB, triple-buffered V
  __shared__ __align__(16) bf16_t Pl[2][32][KT];    // 32 KB
  __shared__ __align__(16) float  PMx[2][64][4];    // partial max per quarter
  __shared__ __align__(16) float  PSx[2][64][4];    // partial sum per quarter

  const int bi = blockIdx.x;
  const int xcd = bi & 7, slot = bi >> 3;
  const int b  = xcd >> 1;
  const int q0 = ((xcd & 1) * 32 + slot) * 64;

  const int t = threadIdx.x, wid = t >> 6, lane = t & 63;
  const int l4 = lane >> 4, lm = lane & 15;
  const int rh = wid & 1, cg = wid >> 1;
  const int pswz = (lm & 7) << 3;

  const f32x4 z4 = {0.f, 0.f, 0.f, 0.f};

  // --- V staging sources (swizzle folded into global address) ---
  const int vr  = lane >> 3;
  const int msw = ((lane & 7) ^ vr) << 3;
  const bf16_t* vsrc[4];
#pragma unroll
  for (int u = 0; u < 4; ++u)
    vsrc[u] = Vh + ((size_t)(b * C_ + 32 * wid + 8 * u + vr)) * N_ + msw;

  // prologue: stage key-blocks 0 -> buf0, 64 -> buf1
#pragma unroll
  for (int u = 0; u < 4; ++u) gld_lds16(vsrc[u], &Vt[0][32 * wid + 8 * u][0]);
#pragma unroll
  for (int u = 0; u < 4; ++u) gld_lds16(vsrc[u] + 64, &Vt[1][32 * wid + 8 * u][0]);

  const bf16_t* kbase = Kh + ((size_t)(b * N_ + cg * 64 + lm)) * D_ + l4 * 8;

  bf16x8_t qf[2];
#pragma unroll
  for (int rt2 = 0; rt2 < 2; ++rt2)
    qf[rt2] = *(const bf16x8_t*)(Qh + ((size_t)(b * N_ + q0 + rh * 32 + rt2 * 16 + lm)) * D_ + l4 * 8);

  f32x4 acc[2][4];
#pragma unroll
  for (int rt2 = 0; rt2 < 2; ++rt2)
#pragma unroll
    for (int ct = 0; ct < 4; ++ct) acc[rt2][ct] = z4;
  float m_run[2] = {-1e30f, -1e30f}, l_run[2] = {0.f, 0.f};

  int bufc = 0;   // LDS buffer holding the current substep's V data
#pragma unroll 1
  for (int it = 0; it < N_ / KT; ++it) {
    // ---- K fragments for this iter (compiler inserts its own vmcnt wait) ----
    bf16x8_t kf[4];
#pragma unroll
    for (int mt = 0; mt < 4; ++mt)
      kf[mt] = *(const bf16x8_t*)(kbase + (size_t)(it * KT + mt * 16) * D_);

    // ---- S quarter: 32 q-rows x 64 keys (distinct per wave) ----
    f32x4 S[2][4];
#pragma unroll
    for (int rt2 = 0; rt2 < 2; ++rt2)
#pragma unroll
      for (int mt = 0; mt < 4; ++mt)
        S[rt2][mt] = __builtin_amdgcn_mfma_f32_16x16x32_bf16(kf[mt], qf[rt2], z4, 0, 0, 0);

    // ---- per-row partial max ----
    float pmx[2];
#pragma unroll
    for (int rt2 = 0; rt2 < 2; ++rt2) {
      float a0 = fmaxf(fmaxf(S[rt2][0][0], S[rt2][0][1]), fmaxf(S[rt2][0][2], S[rt2][0][3]));
      float a1 = fmaxf(fmaxf(S[rt2][1][0], S[rt2][1][1]), fmaxf(S[rt2][1][2], S[rt2][1][3]));
      float a2 = fmaxf(fmaxf(S[rt2][2][0], S[rt2][2][1]), fmaxf(S[rt2][2][2], S[rt2][2][3]));
      float a3 = fmaxf(fmaxf(S[rt2][3][0], S[rt2][3][1]), fmaxf(S[rt2][3][2], S[rt2][3][3]));
      float v = fmaxf(fmaxf(a0, a1), fmaxf(a2, a3));
      v = fmaxf(v, __shfl_xor(v, 16));
      v = fmaxf(v, __shfl_xor(v, 32));
      pmx[rt2] = v;
    }
    if (lane < 32) PMx[rh][lane][cg] = (lane < 16) ? pmx[0] : pmx[1];
    asm volatile("s_waitcnt lgkmcnt(0)" ::: "memory");   // B1 (LDS only)
    __builtin_amdgcn_s_barrier();

    // ---- combine maxes ----
    float sc[2], nm[2]; int chg[2];
#pragma unroll
    for (int rt2 = 0; rt2 < 2; ++rt2) {
      const f32x4 pv = *(const f32x4*)&PMx[rh][rt2 * 16 + lm][0];
      const float tm = fmaxf(fmaxf(pv[0], pv[1]), fmaxf(pv[2], pv[3]));
      const float mo = m_run[rt2];
      nm[rt2]  = fmaxf(mo, tm);
      chg[rt2] = tm > mo;
      sc[rt2]  = __builtin_amdgcn_exp2f(mo - nm[rt2]);
      m_run[rt2] = nm[rt2];
    }

    // ---- exp2, P writes, partial sums ----
    float psx[2];
#pragma unroll
    for (int rt2 = 0; rt2 < 2; ++rt2) {
      float s = 0.f;
      const int prow = rt2 * 16 + lm;
#pragma unroll
      for (int mt = 0; mt < 4; ++mt) {
        const float p0 = __builtin_amdgcn_exp2f(S[rt2][mt][0] - nm[rt2]);
        const float p1 = __builtin_amdgcn_exp2f(S[rt2][mt][1] - nm[rt2]);
        const float p2 = __builtin_amdgcn_exp2f(S[rt2][mt][2] - nm[rt2]);
        const float p3 = __builtin_amdgcn_exp2f(S[rt2][mt][3] - nm[rt2]);
        s += (p0 + p1) + (p2 + p3);
        bf16x4_t w4 = {(bf16_t)p0, (bf16_t)p1, (bf16_t)p2, (bf16_t)p3};
        *(bf16x4_t*)&Pl[rh][prow][(cg * 64 + 16 * mt + 4 * l4) ^ pswz] = w4;
      }
      s += __shfl_xor(s, 16);
      s += __shfl_xor(s, 32);
      psx[rt2] = s;
    }
    if (lane < 32) PSx[rh][lane][cg] = (lane < 16) ? psx[0] : psx[1];

    if (__any(chg[0] || chg[1])) {
#pragma unroll
      for (int rt2 = 0; rt2 < 2; ++rt2)
#pragma unroll
        for (int ct = 0; ct < 4; ++ct) acc[rt2][ct] *= sc[rt2];
    }
    asm volatile("s_waitcnt lgkmcnt(0)" ::: "memory");   // B2 (LDS only)
    __builtin_amdgcn_s_barrier();

    // ---- l update ----
#pragma unroll
    for (int rt2 = 0; rt2 < 2; ++rt2) {
      const f32x4 sv = *(const f32x4*)&PSx[rh][rt2 * 16 + lm][0];
      l_run[rt2] = l_run[rt2] * sc[rt2] + ((sv[0] + sv[1]) + (sv[2] + sv[3]));
    }

    // ---- PV: 4 substeps x 64 keys; triple-buffered, counted vmcnt ----
#pragma unroll
    for (int s4 = 0; s4 < 4; ++s4) {
      if (s4 == 0)
        asm volatile("s_waitcnt vmcnt(4) lgkmcnt(0)" ::: "memory");
      else
        asm volatile("s_waitcnt vmcnt(4)" ::: "memory");
      __builtin_amdgcn_s_barrier();

      // stage substep s4+2 into buffer bufc+2 (mod 3)
      const int knx = (it * KT + (s4 + 2) * 64) & (N_ - 1);
      const int bst = (bufc < 1) ? bufc + 2 : bufc - 1;
#pragma unroll
      for (int u = 0; u < 4; ++u)
        gld_lds16(vsrc[u] + knx, &Vt[bst][32 * wid + 8 * u][0]);

      bf16x8_t pa[2][2];
#pragma unroll
      for (int rt2 = 0; rt2 < 2; ++rt2)
#pragma unroll
        for (int kc = 0; kc < 2; ++kc)
          pa[rt2][kc] = *(const bf16x8_t*)&Pl[rh][rt2 * 16 + lm][(s4 * 64 + kc * 32 + 8 * l4) ^ pswz];
#pragma unroll
      for (int ct = 0; ct < 4; ++ct) {
#pragma unroll
        for (int kc = 0; kc < 2; ++kc) {
          const bf16x8_t vf = *(const bf16x8_t*)&Vt[bufc][cg * 64 + ct * 16 + lm][(kc * 32 + 8 * l4) ^ pswz];
#pragma unroll
          for (int rt2 = 0; rt2 < 2; ++rt2)
            acc[rt2][ct] = __builtin_amdgcn_mfma_f32_16x16x32_bf16(vf, pa[rt2][kc], acc[rt2][ct], 0, 0, 0);
        }
      }
      bufc = (bufc == 2) ? 0 : bufc + 1;
    }
  }

  // ---- epilogue ----
  const float g = gamma[0];
  const int n = q0 + rh * 32 + lm;
#pragma unroll
  for (int rt2 = 0; rt2 < 2; ++rt2) {
    const float inv = 1.f / l_run[rt2];
#pragma unroll
    for (int ct = 0; ct < 4; ++ct) {
#pragma unroll
      for (int r = 0; r < 4; ++r) {
        const int c = cg * 64 + ct * 16 + 4 * l4 + r;
        const size_t idx = ((size_t)(b * C_ + c)) * N_ + n + rt2 * 16;
        out[idx] = g * (acc[rt2][ct][r] * inv) + x[idx];
      }
    }
  }
}

extern "C" void kernel_launch(void* const* d_in, const int* in_sizes, int n_in,
                              void* d_out, int out_size, void* d_ws, size_t ws_size,
                              hipStream_t stream) {
  const float* x     = (const float*)d_in[0];
  const float* wq    = (const float*)d_in[1];
  const float* bq    = (const float*)d_in[2];
  const float* wk    = (const float*)d_in[3];
  const float* bk    = (const float*)d_in[4];
  const float* wv    = (const float*)d_in[5];
  const float* bv    = (const float*)d_in[6];
  const float* gamma = (const float*)d_in[7];
  float* out = (float*)d_out;

  bf16_t* Qh  = (bf16_t*)d_ws;
  bf16_t* Kh  = Qh + (size_t)B_ * N_ * D_;
  bf16_t* Vh  = Kh + (size_t)B_ * N_ * D_;
  bf16_t* Wb  = Vh + (size_t)B_ * C_ * N_;
  bf16_t* xbT = Wb + (size_t)320 * C_;

  cast_kernel<<<1344, 256, 0, stream>>>(x, wq, wk, wv, xbT, Wb);
  proj_kernel<<<256, 256, 0, stream>>>(Wb, xbT, bq, bk, bv, Qh, Kh, Vh);
  attn_kernel<<<256, 512, 0, stream>>>(Qh, Kh, Vh, x, gamma, out);
}

// Round 5
// 104.524 us; speedup vs baseline: 3.5786x; 1.0962x over previous
//
#include <hip/hip_runtime.h>
#include <hip/hip_bf16.h>
#include <stdint.h>

#define B_ 4
#define C_ 256
#define N_ 4096
#define D_ 32
#define KT 256   // keys per outer iteration (softmax tile)

typedef __bf16 bf16_t;
typedef __bf16 bf16x4_t __attribute__((ext_vector_type(4)));
typedef __bf16 bf16x8_t __attribute__((ext_vector_type(8)));
typedef float  f32x4    __attribute__((ext_vector_type(4)));

// ---------------------------------------------------------------------------
// fused cast: blocks <1024 transpose+cast x -> xbT bf16 [B][N][C];
// blocks >=1024 cast W (wq|wk|wv) -> Wb bf16 [320][256]
// ---------------------------------------------------------------------------
__global__ __launch_bounds__(256) void cast_kernel(
    const float* __restrict__ x,
    const float* __restrict__ wq, const float* __restrict__ wk,
    const float* __restrict__ wv,
    bf16_t* __restrict__ xbT, bf16_t* __restrict__ Wb)
{
  const int bid = blockIdx.x;
  const int t = threadIdx.x;
  if (bid >= 1024) {
    const int gr = bid - 1024;   // 0..319
    float v;
    if (gr < 32)      v = wq[gr * C_ + t];
    else if (gr < 64) v = wk[(gr - 32) * C_ + t];
    else              v = wv[(gr - 64) * C_ + t];
    Wb[gr * C_ + t] = (bf16_t)v;
    return;
  }
  __shared__ float xs[64][65];
  const int n0 = (bid & 63) * 64;
  const int c0 = ((bid >> 6) & 3) * 64;
  const int b  = bid >> 8;

  const int lr = t >> 4;
  const int lc = (t & 15) * 4;
#pragma unroll
  for (int i = 0; i < 4; ++i) {
    const f32x4 v = *(const f32x4*)(x + ((size_t)(b * C_ + c0 + lr + i * 16)) * N_ + n0 + lc);
    xs[lr + i * 16][lc + 0] = v[0];
    xs[lr + i * 16][lc + 1] = v[1];
    xs[lr + i * 16][lc + 2] = v[2];
    xs[lr + i * 16][lc + 3] = v[3];
  }
  __syncthreads();
  const int nr = t >> 2;
  const int cb = (t & 3) * 16;
  bf16_t tmp[16];
#pragma unroll
  for (int j = 0; j < 16; ++j) tmp[j] = (bf16_t)xs[cb + j][nr];
  bf16_t* dst = xbT + ((size_t)(b * N_ + n0 + nr)) * C_ + c0 + cb;
  *(bf16x8_t*)dst       = *(bf16x8_t*)&tmp[0];
  *(bf16x8_t*)(dst + 8) = *(bf16x8_t*)&tmp[8];
}

// ---------------------------------------------------------------------------
// Projection GEMM: Wb[320][256] x xbT^T -> Q/K/V bf16 MFMA, no LDS.
// Q rows pre-scaled by log2(e) so attention softmax runs in exp2 domain.
// ---------------------------------------------------------------------------
__global__ __launch_bounds__(256) void proj_kernel(
    const bf16_t* __restrict__ Wb, const bf16_t* __restrict__ xbT,
    const float* __restrict__ bq, const float* __restrict__ bk,
    const float* __restrict__ bv,
    bf16_t* __restrict__ Qh, bf16_t* __restrict__ Kh, bf16_t* __restrict__ Vh)
{
  const int bi = blockIdx.x;
  const int b  = bi & 3;
  const int n0 = (bi >> 2) * 64;
  const int t = threadIdx.x, w = t >> 6, lane = t & 63;
  const int l4 = lane >> 4, lm = lane & 15;

  const f32x4 z4 = {0.f, 0.f, 0.f, 0.f};
  f32x4 acc[5][4];
#pragma unroll
  for (int rt = 0; rt < 5; ++rt)
#pragma unroll
    for (int ct = 0; ct < 4; ++ct) acc[rt][ct] = z4;

#pragma unroll 1
  for (int k0 = 0; k0 < C_; k0 += 64) {
    bf16x8_t af[5][2], bfr[4][2];
#pragma unroll
    for (int rt = 0; rt < 5; ++rt)
#pragma unroll
      for (int kc = 0; kc < 2; ++kc)
        af[rt][kc] = *(const bf16x8_t*)(Wb + (size_t)(w * 80 + rt * 16 + lm) * C_ + k0 + kc * 32 + l4 * 8);
#pragma unroll
    for (int ct = 0; ct < 4; ++ct)
#pragma unroll
      for (int kc = 0; kc < 2; ++kc)
        bfr[ct][kc] = *(const bf16x8_t*)(xbT + ((size_t)(b * N_ + n0 + ct * 16 + lm)) * C_ + k0 + kc * 32 + l4 * 8);
#pragma unroll
    for (int rt = 0; rt < 5; ++rt)
#pragma unroll
      for (int ct = 0; ct < 4; ++ct)
#pragma unroll
        for (int kc = 0; kc < 2; ++kc)
          acc[rt][ct] = __builtin_amdgcn_mfma_f32_16x16x32_bf16(af[rt][kc], bfr[ct][kc], acc[rt][ct], 0, 0, 0);
  }

#pragma unroll
  for (int rt = 0; rt < 5; ++rt)
#pragma unroll
    for (int r = 0; r < 4; ++r) {
      const int gr = w * 80 + rt * 16 + 4 * l4 + r;
      const float bias = (gr < 32) ? bq[gr] : (gr < 64) ? bk[gr - 32] : bv[gr - 64];
#pragma unroll
      for (int ct = 0; ct < 4; ++ct) {
        const int n = n0 + ct * 16 + lm;
        float v = acc[rt][ct][r] + bias;
        if (gr < 32) {
          v *= 1.44269504088896f;
          Qh[((size_t)(b * N_ + n)) * D_ + gr] = (bf16_t)v;
        } else if (gr < 64) {
          Kh[((size_t)(b * N_ + n)) * D_ + (gr - 32)] = (bf16_t)v;
        } else {
          Vh[((size_t)(b * C_ + (gr - 64))) * N_ + n] = (bf16_t)v;
        }
      }
    }
}

// ---------------------------------------------------------------------------
// Flash attention, channel-partitioned waves, V DIRECT FROM L2 (no V in LDS):
//  8 waves = 8 channel-groups (32 ch), each wave spans all 64 q-rows.
//  Keys split 8-way per iter for S/softmax (zero redundancy).
//  LDS: only P[64][256] (XOR-swizzled) + PMx/PSx partials = 36 KB.
//  Exactly 2 lgkm-only barriers per 256-key iter; PV substeps barrier-free
//  with depth-2 register prefetch of V fragments; K prefetched 1 iter ahead.
// ---------------------------------------------------------------------------
__global__ __launch_bounds__(512, 2) void attn_kernel(
    const bf16_t* __restrict__ Qh, const bf16_t* __restrict__ Kh,
    const bf16_t* __restrict__ Vh, const float* __restrict__ x,
    const float* __restrict__ gamma, float* __restrict__ out)
{
  __shared__ __align__(16) bf16_t Pl[64][KT];   // 32 KB, key-index XOR-swizzled per row
  __shared__ __align__(16) float  PMx[64][8];   // partial max per q-row per wave
  __shared__ __align__(16) float  PSx[64][8];   // partial sum per q-row per wave

  const int bi = blockIdx.x;
  const int xcd = bi & 7, slot = bi >> 3;
  const int b  = xcd >> 1;                 // 2 XCDs per batch -> K,V,Q L2-resident
  const int q0 = ((xcd & 1) * 32 + slot) * 64;

  const int t = threadIdx.x, w = t >> 6, lane = t & 63;
  const int l4 = lane >> 4, lm = lane & 15;
  const int swz = (lm & 7) << 3;           // row-dependent key XOR (bijective per row)

  const f32x4 z4 = {0.f, 0.f, 0.f, 0.f};

  // Q fragments: 4 q-subtiles of 16 (held whole kernel)
  bf16x8_t qf[4];
#pragma unroll
  for (int rt = 0; rt < 4; ++rt)
    qf[rt] = *(const bf16x8_t*)(Qh + ((size_t)(b * N_ + q0 + rt * 16 + lm)) * D_ + l4 * 8);

  // K base: this wave's 32-key slice within each 256-key tile
  const bf16_t* kbase = Kh + ((size_t)(b * N_ + w * 32 + lm)) * D_ + l4 * 8;
  // V base: this wave's 32 channels (2 ct sub-tiles of 16)
  const bf16_t* vbase = Vh + ((size_t)(b * C_ + w * 32 + lm)) * N_ + l4 * 8;

  f32x4 acc[2][4];   // [ct][rt] : 32 ch x 64 q
#pragma unroll
  for (int ct = 0; ct < 2; ++ct)
#pragma unroll
    for (int rt = 0; rt < 4; ++rt) acc[ct][rt] = z4;
  float m_run[4] = {-1e30f, -1e30f, -1e30f, -1e30f};
  float l_run[4] = {0.f, 0.f, 0.f, 0.f};

  // prologue: K tile 0; V fragments for substeps 0 and 1
  bf16x8_t kf[2], kn[2];
#pragma unroll
  for (int mt = 0; mt < 2; ++mt)
    kf[mt] = *(const bf16x8_t*)(kbase + (size_t)(mt * 16) * D_);
  bf16x8_t vf0[2][2], vf1[2][2];   // [ct][kc], ping-pong banks
#pragma unroll
  for (int ct = 0; ct < 2; ++ct)
#pragma unroll
    for (int kc = 0; kc < 2; ++kc) {
      vf0[ct][kc] = *(const bf16x8_t*)(vbase + (size_t)(ct * 16) * N_ + kc * 32);
      vf1[ct][kc] = *(const bf16x8_t*)(vbase + (size_t)(ct * 16) * N_ + 64 + kc * 32);
    }

#pragma unroll 1
  for (int it = 0; it < N_ / KT; ++it) {
    // ---- S: 64 q x this wave's 32 keys ----
    f32x4 S[4][2];
#pragma unroll
    for (int rt = 0; rt < 4; ++rt)
#pragma unroll
      for (int mt = 0; mt < 2; ++mt)
        S[rt][mt] = __builtin_amdgcn_mfma_f32_16x16x32_bf16(kf[mt], qf[rt], z4, 0, 0, 0);

    // ---- per-q-row partial max over 32 keys ----
    float pmx[4];
#pragma unroll
    for (int rt = 0; rt < 4; ++rt) {
      float a0 = fmaxf(fmaxf(S[rt][0][0], S[rt][0][1]), fmaxf(S[rt][0][2], S[rt][0][3]));
      float a1 = fmaxf(fmaxf(S[rt][1][0], S[rt][1][1]), fmaxf(S[rt][1][2], S[rt][1][3]));
      float v = fmaxf(a0, a1);
      v = fmaxf(v, __shfl_xor(v, 16));
      v = fmaxf(v, __shfl_xor(v, 32));
      pmx[rt] = v;
    }
    {
      const float pw = (l4 == 0) ? pmx[0] : (l4 == 1) ? pmx[1] : (l4 == 2) ? pmx[2] : pmx[3];
      PMx[l4 * 16 + lm][w] = pw;
    }
    asm volatile("s_waitcnt lgkmcnt(0)" ::: "memory");   // B1
    __builtin_amdgcn_s_barrier();

    // ---- combine maxes across 8 key-slices ----
    float nm[4], sc[4]; int chg = 0;
#pragma unroll
    for (int rt = 0; rt < 4; ++rt) {
      const f32x4 p0 = *(const f32x4*)&PMx[rt * 16 + lm][0];
      const f32x4 p1 = *(const f32x4*)&PMx[rt * 16 + lm][4];
      const float tm = fmaxf(fmaxf(fmaxf(p0[0], p0[1]), fmaxf(p0[2], p0[3])),
                             fmaxf(fmaxf(p1[0], p1[1]), fmaxf(p1[2], p1[3])));
      const float mo = m_run[rt];
      nm[rt] = fmaxf(mo, tm);
      chg |= (tm > mo);
      sc[rt] = __builtin_amdgcn_exp2f(mo - nm[rt]);
      m_run[rt] = nm[rt];
    }

    // ---- exp2, P writes (own 32-key slice, all 64 q), partial sums ----
    float psx[4];
#pragma unroll
    for (int rt = 0; rt < 4; ++rt) {
      float s = 0.f;
      const int prow = rt * 16 + lm;
#pragma unroll
      for (int mt = 0; mt < 2; ++mt) {
        const float p0 = __builtin_amdgcn_exp2f(S[rt][mt][0] - nm[rt]);
        const float p1 = __builtin_amdgcn_exp2f(S[rt][mt][1] - nm[rt]);
        const float p2 = __builtin_amdgcn_exp2f(S[rt][mt][2] - nm[rt]);
        const float p3 = __builtin_amdgcn_exp2f(S[rt][mt][3] - nm[rt]);
        s += (p0 + p1) + (p2 + p3);
        bf16x4_t w4 = {(bf16_t)p0, (bf16_t)p1, (bf16_t)p2, (bf16_t)p3};
        *(bf16x4_t*)&Pl[prow][(w * 32 + mt * 16 + 4 * l4) ^ swz] = w4;
      }
      s += __shfl_xor(s, 16);
      s += __shfl_xor(s, 32);
      psx[rt] = s;
    }
    {
      const float pw = (l4 == 0) ? psx[0] : (l4 == 1) ? psx[1] : (l4 == 2) ? psx[2] : psx[3];
      PSx[l4 * 16 + lm][w] = pw;
    }

    if (__any(chg)) {
#pragma unroll
      for (int ct = 0; ct < 2; ++ct)
#pragma unroll
        for (int rt = 0; rt < 4; ++rt) acc[ct][rt] *= sc[rt];
    }

    // prefetch next iter's K slice (in flight across PV)
    const int k0n = ((it + 1) * KT) & (N_ - 1);
#pragma unroll
    for (int mt = 0; mt < 2; ++mt)
      kn[mt] = *(const bf16x8_t*)(kbase + (size_t)(k0n + mt * 16) * D_);

    asm volatile("s_waitcnt lgkmcnt(0)" ::: "memory");   // B2
    __builtin_amdgcn_s_barrier();

    // ---- l update ----
#pragma unroll
    for (int rt = 0; rt < 4; ++rt) {
      const f32x4 s0 = *(const f32x4*)&PSx[rt * 16 + lm][0];
      const f32x4 s1 = *(const f32x4*)&PSx[rt * 16 + lm][4];
      l_run[rt] = l_run[rt] * sc[rt] +
                  (((s0[0] + s0[1]) + (s0[2] + s0[3])) + ((s1[0] + s1[1]) + (s1[2] + s1[3])));
    }

    // ---- PV: 4 barrier-free substeps x 64 keys; V depth-2 reg prefetch ----
#pragma unroll
    for (int s4 = 0; s4 < 4; ++s4) {
      bf16x8_t pa[4][2];
#pragma unroll
      for (int rt = 0; rt < 4; ++rt)
#pragma unroll
        for (int kc = 0; kc < 2; ++kc)
          pa[rt][kc] = *(const bf16x8_t*)&Pl[rt * 16 + lm][(s4 * 64 + kc * 32 + l4 * 8) ^ swz];
      if ((s4 & 1) == 0) {
#pragma unroll
        for (int ct = 0; ct < 2; ++ct)
#pragma unroll
          for (int kc = 0; kc < 2; ++kc)
#pragma unroll
            for (int rt = 0; rt < 4; ++rt)
              acc[ct][rt] = __builtin_amdgcn_mfma_f32_16x16x32_bf16(vf0[ct][kc], pa[rt][kc], acc[ct][rt], 0, 0, 0);
        const int knx = (it * KT + (s4 + 2) * 64) & (N_ - 1);
#pragma unroll
        for (int ct = 0; ct < 2; ++ct)
#pragma unroll
          for (int kc = 0; kc < 2; ++kc)
            vf0[ct][kc] = *(const bf16x8_t*)(vbase + (size_t)(ct * 16) * N_ + knx + kc * 32);
      } else {
#pragma unroll
        for (int ct = 0; ct < 2; ++ct)
#pragma unroll
          for (int kc = 0; kc < 2; ++kc)
#pragma unroll
            for (int rt = 0; rt < 4; ++rt)
              acc[ct][rt] = __builtin_amdgcn_mfma_f32_16x16x32_bf16(vf1[ct][kc], pa[rt][kc], acc[ct][rt], 0, 0, 0);
        const int knx = (it * KT + (s4 + 2) * 64) & (N_ - 1);
#pragma unroll
        for (int ct = 0; ct < 2; ++ct)
#pragma unroll
          for (int kc = 0; kc < 2; ++kc)
            vf1[ct][kc] = *(const bf16x8_t*)(vbase + (size_t)(ct * 16) * N_ + knx + kc * 32);
      }
    }

#pragma unroll
    for (int mt = 0; mt < 2; ++mt) kf[mt] = kn[mt];
  }

  // ---- epilogue: out = gamma*acc/l + x (64B-coalesced runs) ----
  const float g = gamma[0];
#pragma unroll
  for (int rt = 0; rt < 4; ++rt) {
    const float inv = 1.f / l_run[rt];
    const int n = q0 + rt * 16 + lm;
#pragma unroll
    for (int ct = 0; ct < 2; ++ct) {
#pragma unroll
      for (int r = 0; r < 4; ++r) {
        const int c = w * 32 + ct * 16 + 4 * l4 + r;
        const size_t idx = ((size_t)(b * C_ + c)) * N_ + n;
        out[idx] = g * (acc[ct][rt][r] * inv) + x[idx];
      }
    }
  }
}

extern "C" void kernel_launch(void* const* d_in, const int* in_sizes, int n_in,
                              void* d_out, int out_size, void* d_ws, size_t ws_size,
                              hipStream_t stream) {
  const float* x     = (const float*)d_in[0];
  const float* wq    = (const float*)d_in[1];
  const float* bq    = (const float*)d_in[2];
  const float* wk    = (const float*)d_in[3];
  const float* bk    = (const float*)d_in[4];
  const float* wv    = (const float*)d_in[5];
  const float* bv    = (const float*)d_in[6];
  const float* gamma = (const float*)d_in[7];
  float* out = (float*)d_out;

  bf16_t* Qh  = (bf16_t*)d_ws;
  bf16_t* Kh  = Qh + (size_t)B_ * N_ * D_;
  bf16_t* Vh  = Kh + (size_t)B_ * N_ * D_;
  bf16_t* Wb  = Vh + (size_t)B_ * C_ * N_;
  bf16_t* xbT = Wb + (size_t)320 * C_;

  cast_kernel<<<1344, 256, 0, stream>>>(x, wq, wk, wv, xbT, Wb);
  proj_kernel<<<256, 256, 0, stream>>>(Wb, xbT, bq, bk, bv, Qh, Kh, Vh);
  attn_kernel<<<256, 512, 0, stream>>>(Qh, Kh, Vh, x, gamma, out);
}